// Round 1
// baseline (964.265 us; speedup 1.0000x reference)
//
#include <hip/hip_runtime.h>
#include <math.h>

#define N_TOK 8192
#define DIM 1024
#define FF 4096
#define NE 8
#define BM 256
#define BN 128
#define BK 64
#define MAXT 72                     // max sum of ceil(count_e/BM) = 16384/256 + 8
#define SLOT_CAP (N_TOK*2 + NE*BM)  // 18432

typedef float f32x4 __attribute__((ext_vector_type(4)));
typedef _Float16 f16x8 __attribute__((ext_vector_type(8)));
typedef unsigned int u32x4 __attribute__((ext_vector_type(4)));
typedef unsigned short u16x4 __attribute__((ext_vector_type(4)));

__device__ __forceinline__ unsigned short f2h(float f) {
    _Float16 h = (_Float16)f;
    return __builtin_bit_cast(unsigned short, h);
}

// ---------------- Router: fp32 logits, top-2, softmax, counts, x->fp16 ----------------
__global__ __launch_bounds__(256) void k_router(
    const float* __restrict__ x, const float* __restrict__ Wr,
    unsigned short* __restrict__ xh, int* __restrict__ ctl,
    int* __restrict__ tok2e, float* __restrict__ tok2w)
{
    __shared__ float wr[NE * DIM];
    const int t = threadIdx.x;
#pragma unroll
    for (int i = 0; i < (NE * DIM) / 256; ++i) wr[i * 256 + t] = Wr[i * 256 + t];
    __syncthreads();

    const int lane = t & 63;
    const int n = blockIdx.x * 4 + (t >> 6);
    const float* xr = x + (size_t)n * DIM;
    unsigned short* xhr = xh + (size_t)n * DIM;

    float acc[NE];
#pragma unroll
    for (int e = 0; e < NE; ++e) acc[e] = 0.f;

#pragma unroll
    for (int j = 0; j < DIM / 64; ++j) {
        int d = j * 64 + lane;
        float v = xr[d];
        xhr[d] = f2h(v);
#pragma unroll
        for (int e = 0; e < NE; ++e) acc[e] += v * wr[e * DIM + d];
    }
#pragma unroll
    for (int off = 32; off >= 1; off >>= 1) {
#pragma unroll
        for (int e = 0; e < NE; ++e) acc[e] += __shfl_xor(acc[e], off);
    }
    if (lane == 0) {
        int e0 = 0; float v0 = acc[0];
#pragma unroll
        for (int e = 1; e < NE; ++e) if (acc[e] > v0) { v0 = acc[e]; e0 = e; }
        int e1 = -1; float v1 = -1e30f;
#pragma unroll
        for (int e = 0; e < NE; ++e) if (e != e0 && acc[e] > v1) { v1 = acc[e]; e1 = e; }
        float tt = expf(v1 - v0);
        float w0 = 1.f / (1.f + tt);
        float w1 = tt / (1.f + tt);
        tok2e[2 * n] = e0; tok2e[2 * n + 1] = e1;
        tok2w[2 * n] = w0; tok2w[2 * n + 1] = w1;
        atomicAdd(&ctl[e0], 1);
        atomicAdd(&ctl[e1], 1);
    }
}

// ---------------- Setup: padded offsets, tile map, pad-slot fill ----------------
__global__ void k_setup(int* __restrict__ ctl, int* __restrict__ tos, float* __restrict__ gos)
{
    if (threadIdx.x != 0) return;
    int run = 0, T = 0;
    for (int e = 0; e < NE; ++e) {
        ctl[16 + e] = run;
        int c = ctl[e];
        int mt = (c + BM - 1) / BM;
        for (int j = 0; j < mt; ++j) { ctl[40 + T] = e; ctl[120 + T] = run + j * BM; ++T; }
        for (int s = run + c; s < run + mt * BM; ++s) { tos[s] = 0; gos[s] = 0.f; }
        run += mt * BM;
    }
    ctl[16 + NE] = run;
    ctl[32] = T;
}

// ---------------- Scatter: token -> slot ----------------
__global__ __launch_bounds__(256) void k_scatter(
    const int* __restrict__ tok2e, const float* __restrict__ tok2w,
    int* __restrict__ ctl, int* __restrict__ tos, float* __restrict__ gos)
{
    const int n = blockIdx.x * 256 + threadIdx.x;
#pragma unroll
    for (int k = 0; k < 2; ++k) {
        int e = tok2e[2 * n + k];
        int pos = atomicAdd(&ctl[8 + e], 1);
        int slot = ctl[16 + e] + pos;
        tos[slot] = n;
        gos[slot] = tok2w[2 * n + k];
    }
}

// ---------------- Grouped GEMM: PHASE 1 = gelu(X@W1)->H, PHASE 2 = H@W2 -> +=out ----------------
template <int PHASE>
__global__ __launch_bounds__(512) void k_gemm(
    const unsigned short* __restrict__ Asrc, const float* __restrict__ Wsrc,
    unsigned short* __restrict__ Hout, float* __restrict__ Out,
    const int* __restrict__ ctl, const int* __restrict__ tos,
    const float* __restrict__ gos)
{
    constexpr int KD = (PHASE == 1) ? DIM : FF;
    constexpr int ND = (PHASE == 1) ? FF : DIM;

    const int tidx = blockIdx.y;
    if (tidx >= ctl[32]) return;
    const int e = ctl[40 + tidx];
    const int m0 = ctl[120 + tidx];
    const int n0 = blockIdx.x * BN;
    const float* W = Wsrc + (size_t)e * KD * ND;

    __shared__ __align__(16) unsigned short Al[BM * 72];  // [row][k], row stride 72 elems
    __shared__ __align__(16) unsigned short Bl[BN * 64];  // [n][k] XOR-swizzled

    const int t = threadIdx.x;
    const int lane = t & 63;
    const int wv = t >> 6;
    const int wm = wv >> 1, wn = wv & 1;  // 4x2 wave grid, 64x64 per wave

    // A staging: thread -> (row = t>>1, half = t&1)
    const int arow = t >> 1;
    const int acol = (t & 1) * 32;
    size_t abase;
    if (PHASE == 1) abase = (size_t)tos[m0 + arow] * KD;
    else            abase = (size_t)(m0 + arow) * KD;
    const unsigned short* Ap = Asrc + abase + acol;
    unsigned short* Alw = &Al[arow * 72 + acol];

    // B staging: thread -> (n = (t&31)*4, k = (t>>5)*4); transpose+convert fp32->fp16
    const int tn = (t & 31) * 4;
    const int tk = (t >> 5) * 4;
    const float* Wp = W + (size_t)tk * ND + n0 + tn;
    char* Blc = reinterpret_cast<char*>(Bl);

    f32x4 acc[4][4];
#pragma unroll
    for (int a = 0; a < 4; ++a)
#pragma unroll
        for (int b = 0; b < 4; ++b) acc[a][b] = f32x4{0.f, 0.f, 0.f, 0.f};

    for (int k0 = 0; k0 < KD; k0 += BK) {
        // ---- stage A (fp16 source, linear) ----
#pragma unroll
        for (int i = 0; i < 4; ++i)
            *reinterpret_cast<u32x4*>(Alw + i * 8) =
                *reinterpret_cast<const u32x4*>(Ap + k0 + i * 8);
        // ---- stage B (fp32 source, convert + transpose into [n][k]) ----
        f32x4 r[4];
#pragma unroll
        for (int rr = 0; rr < 4; ++rr)
            r[rr] = *reinterpret_cast<const f32x4*>(Wp + (size_t)(k0 + rr) * ND);
#pragma unroll
        for (int i = 0; i < 4; ++i) {
            int n = tn + i;
            u16x4 pk = { f2h(r[0][i]), f2h(r[1][i]), f2h(r[2][i]), f2h(r[3][i]) };
            int bo = n * 128 + ((tk * 2) ^ ((n & 7) << 4));
            *reinterpret_cast<u16x4*>(Blc + bo) = pk;
        }
        __syncthreads();
        // ---- compute ----
#pragma unroll
        for (int kc = 0; kc < 2; ++kc) {
            const int krel = kc * 32 + (lane >> 4) * 8;
            f16x8 af[4], bfr[4];
#pragma unroll
            for (int mi = 0; mi < 4; ++mi)
                af[mi] = *reinterpret_cast<const f16x8*>(
                    &Al[(wm * 64 + mi * 16 + (lane & 15)) * 72 + krel]);
#pragma unroll
            for (int ni = 0; ni < 4; ++ni) {
                int col = wn * 64 + ni * 16 + (lane & 15);
                bfr[ni] = *reinterpret_cast<const f16x8*>(
                    Blc + col * 128 + ((krel * 2) ^ ((col & 7) << 4)));
            }
#pragma unroll
            for (int mi = 0; mi < 4; ++mi)
#pragma unroll
                for (int ni = 0; ni < 4; ++ni)
                    acc[mi][ni] = __builtin_amdgcn_mfma_f32_16x16x32_f16(
                        af[mi], bfr[ni], acc[mi][ni], 0, 0, 0);
        }
        __syncthreads();
    }

    // ---- epilogue ----
#pragma unroll
    for (int mi = 0; mi < 4; ++mi) {
#pragma unroll
        for (int rr = 0; rr < 4; ++rr) {
            const int srow = m0 + wm * 64 + mi * 16 + (lane >> 4) * 4 + rr;
            if (PHASE == 1) {
                unsigned short* hr = Hout + (size_t)srow * FF + n0 + wn * 64 + (lane & 15);
#pragma unroll
                for (int ni = 0; ni < 4; ++ni) {
                    float v = acc[mi][ni][rr];
                    float g = 0.5f * v * (1.f + erff(v * 0.70710678118654752f));
                    hr[ni * 16] = f2h(g);
                }
            } else {
                int tok = tos[srow];
                float gate = gos[srow];
                float* orow = Out + (size_t)tok * DIM + n0 + wn * 64 + (lane & 15);
#pragma unroll
                for (int ni = 0; ni < 4; ++ni)
                    atomicAdd(&orow[ni * 16], gate * acc[mi][ni][rr]);
            }
        }
    }
}

// ---------------- launch ----------------
extern "C" void kernel_launch(void* const* d_in, const int* in_sizes, int n_in,
                              void* d_out, int out_size, void* d_ws, size_t ws_size,
                              hipStream_t stream) {
    (void)in_sizes; (void)n_in;
    const float* x  = (const float*)d_in[0];
    const float* Wr = (const float*)d_in[1];
    const float* W1 = (const float*)d_in[2];
    const float* W2 = (const float*)d_in[3];
    float* out = (float*)d_out;
    char* ws = (char*)d_ws;

    // ws layout
    //   0        : ctl (counts[8], cursors[8], off[9], ntiles@32, tile_e@40, tile_m@120)
    //   4096     : tok2e  (2N int)
    //   69632    : tok2w  (2N float)
    //   135168   : token_of_slot (SLOT_CAP int)
    //   208896   : gate_of_slot  (SLOT_CAP float)
    //   282624   : x fp16 (N*D)
    //   17059840 : H fp16 (SLOT_CAP * FF)
    // total 168,054,784 B
    if (ws_size < 168054784ULL) return;

    int*            ctl = (int*)(ws + 0);
    int*            t2e = (int*)(ws + 4096);
    float*          t2w = (float*)(ws + 69632);
    int*            tos = (int*)(ws + 135168);
    float*          gos = (float*)(ws + 208896);
    unsigned short* xh  = (unsigned short*)(ws + 282624);
    unsigned short* H   = (unsigned short*)(ws + 17059840);

    hipMemsetAsync(ctl, 0, 64, stream);                          // counts + cursors
    hipMemsetAsync(d_out, 0, (size_t)out_size * 4, stream);      // atomic accumulate target

    k_router <<<dim3(N_TOK / 4), dim3(256), 0, stream>>>(x, Wr, xh, ctl, t2e, t2w);
    k_setup  <<<dim3(1), dim3(64), 0, stream>>>(ctl, tos, gos);
    k_scatter<<<dim3(N_TOK / 256), dim3(256), 0, stream>>>(t2e, t2w, ctl, tos, gos);
    k_gemm<1><<<dim3(FF / BN, MAXT), dim3(512), 0, stream>>>(xh, W1, H, nullptr, ctl, tos, gos);
    k_gemm<2><<<dim3(DIM / BN, MAXT), dim3(512), 0, stream>>>(H, W2, nullptr, out, ctl, tos, gos);
}

// Round 2
// 858.333 us; speedup vs baseline: 1.1234x; 1.1234x over previous
//
#include <hip/hip_runtime.h>
#include <math.h>

#define N_TOK 8192
#define DIM 1024
#define FF 4096
#define NE 8
#define BM 128
#define BN 128
#define BK 64
#define MAXT 136                     // max sum of ceil(count_e/128) = 16384/128 + 8
#define SLOT_CAP (N_TOK*2 + NE*BM)   // 17408

typedef float f32x4 __attribute__((ext_vector_type(4)));
typedef _Float16 f16x8 __attribute__((ext_vector_type(8)));
typedef unsigned int u32x4 __attribute__((ext_vector_type(4)));

__device__ __forceinline__ unsigned short f2h(float f) {
    _Float16 h = (_Float16)f;
    return __builtin_bit_cast(unsigned short, h);
}

// global -> LDS direct DMA, 16B per lane. lds ptr must be wave-uniform; HW adds lane*16.
__device__ __forceinline__ void gl_lds16(const void* g, void* l) {
    __builtin_amdgcn_global_load_lds(
        (const __attribute__((address_space(1))) void*)g,
        (__attribute__((address_space(3))) void*)l, 16, 0, 0);
}

// ---------------- Router: fp32 logits, top-2, softmax, counts, x->fp16 ----------------
__global__ __launch_bounds__(256) void k_router(
    const float* __restrict__ x, const float* __restrict__ Wr,
    unsigned short* __restrict__ xh, int* __restrict__ ctl,
    int* __restrict__ tok2e, float* __restrict__ tok2w)
{
    __shared__ float wr[NE * DIM];
    const int t = threadIdx.x;
#pragma unroll
    for (int i = 0; i < (NE * DIM) / 256; ++i) wr[i * 256 + t] = Wr[i * 256 + t];
    __syncthreads();

    const int lane = t & 63;
    const int n = blockIdx.x * 4 + (t >> 6);
    const float* xr = x + (size_t)n * DIM;
    unsigned short* xhr = xh + (size_t)n * DIM;

    float acc[NE];
#pragma unroll
    for (int e = 0; e < NE; ++e) acc[e] = 0.f;

#pragma unroll
    for (int j = 0; j < DIM / 64; ++j) {
        int d = j * 64 + lane;
        float v = xr[d];
        xhr[d] = f2h(v);
#pragma unroll
        for (int e = 0; e < NE; ++e) acc[e] += v * wr[e * DIM + d];
    }
#pragma unroll
    for (int off = 32; off >= 1; off >>= 1) {
#pragma unroll
        for (int e = 0; e < NE; ++e) acc[e] += __shfl_xor(acc[e], off);
    }
    if (lane == 0) {
        int e0 = 0; float v0 = acc[0];
#pragma unroll
        for (int e = 1; e < NE; ++e) if (acc[e] > v0) { v0 = acc[e]; e0 = e; }
        int e1 = -1; float v1 = -1e30f;
#pragma unroll
        for (int e = 0; e < NE; ++e) if (e != e0 && acc[e] > v1) { v1 = acc[e]; e1 = e; }
        float tt = expf(v1 - v0);
        tok2e[2 * n] = e0; tok2e[2 * n + 1] = e1;
        tok2w[2 * n] = 1.f / (1.f + tt); tok2w[2 * n + 1] = tt / (1.f + tt);
        atomicAdd(&ctl[e0], 1);
        atomicAdd(&ctl[e1], 1);
    }
}

// ---------------- Setup: padded offsets, tile map, pad-slot fill ----------------
__global__ void k_setup(int* __restrict__ ctl, int* __restrict__ tos, float* __restrict__ gos)
{
    if (threadIdx.x != 0) return;
    int run = 0, T = 0;
    for (int e = 0; e < NE; ++e) {
        ctl[16 + e] = run;
        int c = ctl[e];
        int mt = (c + BM - 1) / BM;
        for (int j = 0; j < mt; ++j) { ctl[40 + T] = e; ctl[176 + T] = run + j * BM; ++T; }
        for (int s = run + c; s < run + mt * BM; ++s) { tos[s] = 0; gos[s] = 0.f; }
        run += mt * BM;
    }
    ctl[16 + NE] = run;
    ctl[32] = T;
}

// ---------------- Scatter: token -> slot ----------------
__global__ __launch_bounds__(256) void k_scatter(
    const int* __restrict__ tok2e, const float* __restrict__ tok2w,
    int* __restrict__ ctl, int* __restrict__ tos, float* __restrict__ gos)
{
    const int n = blockIdx.x * 256 + threadIdx.x;
#pragma unroll
    for (int k = 0; k < 2; ++k) {
        int e = tok2e[2 * n + k];
        int pos = atomicAdd(&ctl[8 + e], 1);
        int slot = ctl[16 + e] + pos;
        tos[slot] = n;
        gos[slot] = tok2w[2 * n + k];
    }
}

// ---------------- W convert: fp32 [E][KD][ND] -> fp16 tile-format [e][kt][n][swz 64k] ----------------
// stored element (k = kt*64 + c*8 + j, n)  at  Wt[((e*KT+kt)*ND + n)*64 + (c ^ (n&7))*8 + j]
__global__ __launch_bounds__(256) void k_wcvt(
    const float* __restrict__ W, unsigned short* __restrict__ Wt, int KD, int ND)
{
    __shared__ unsigned short Lt[64 * 64];
    const int t = threadIdx.x;
    const int e = blockIdx.z, kt = blockIdx.y, n0 = blockIdx.x * 64;
    const int KT = KD >> 6;
    const float* src = W + (size_t)e * KD * ND + (size_t)(kt * 64) * ND + n0;
#pragma unroll
    for (int i = 0; i < 4; ++i) {
        int kl = (t >> 4) + i * 16;
        f32x4 r = *reinterpret_cast<const f32x4*>(src + (size_t)kl * ND + (t & 15) * 4);
        int j = kl & 7, co = kl >> 3;
#pragma unroll
        for (int m = 0; m < 4; ++m) {
            int nl = (t & 15) * 4 + m;
            Lt[nl * 64 + ((co ^ (nl & 7)) << 3) + j] = f2h(r[m]);
        }
    }
    __syncthreads();
    unsigned short* dst = Wt + ((size_t)(e * KT + kt) * ND + n0) * 64 + t * 16;
    *reinterpret_cast<u32x4*>(dst)     = *reinterpret_cast<const u32x4*>(&Lt[t * 16]);
    *reinterpret_cast<u32x4*>(dst + 8) = *reinterpret_cast<const u32x4*>(&Lt[t * 16 + 8]);
}

// ---------------- Grouped GEMM (128x128, BK=64, 4 waves, global_load_lds) ----------------
// PHASE 1: gelu(X@W1) -> H (tile-format). PHASE 2: H@W2 -> gate*atomicAdd(out).
// WH=true: B from fp16 tile-format via gl_lds. WH=false: B reg-staged from fp32.
template <int PHASE, bool WH>
__global__ __launch_bounds__(256) void k_gemm(
    const unsigned short* __restrict__ Asrc, const unsigned short* __restrict__ Bh,
    const float* __restrict__ Bf, unsigned short* __restrict__ Hout,
    float* __restrict__ Out, const int* __restrict__ ctl,
    const int* __restrict__ tos, const float* __restrict__ gos)
{
    constexpr int KD = (PHASE == 1) ? DIM : FF;
    constexpr int ND = (PHASE == 1) ? FF : DIM;
    constexpr int KT = KD / 64;

    const int tidx = blockIdx.y;
    if (tidx >= ctl[32]) return;
    const int e  = ctl[40 + tidx];
    const int m0 = ctl[176 + tidx];
    const int n0 = blockIdx.x * BN;

    __shared__ __align__(16) unsigned short Al[BM * 64];
    __shared__ __align__(16) unsigned short Bl[BN * 64];
    char* Alc = (char*)Al;
    char* Blc = (char*)Bl;

    const int t = threadIdx.x, lane = t & 63, wv = t >> 6;
    const int wm = wv >> 1, wn = wv & 1;

    // per-lane A sources (PHASE1: gathered rows, chunk-swizzle applied on global side)
    const unsigned short* asrc[4];
    if (PHASE == 1) {
        const int swz = ((lane & 7) ^ (lane >> 3)) * 8;
#pragma unroll
        for (int i = 0; i < 4; ++i) {
            int row = i * 32 + wv * 8 + (lane >> 3);
            asrc[i] = Asrc + (size_t)tos[m0 + row] * KD + swz;
        }
    }
    const int lin = wv * 512 + lane * 8;  // per-lane linear elem offset within a 4KB stage chunk

    f32x4 acc[4][4];
#pragma unroll
    for (int a = 0; a < 4; ++a)
#pragma unroll
        for (int b = 0; b < 4; ++b) acc[a][b] = f32x4{0.f, 0.f, 0.f, 0.f};

    for (int kt = 0; kt < KT; ++kt) {
        // ---- stage A ----
        if (PHASE == 1) {
#pragma unroll
            for (int i = 0; i < 4; ++i)
                gl_lds16(asrc[i] + kt * 64, Al + i * 2048 + wv * 512);
        } else {
            const unsigned short* ab = Asrc + ((size_t)kt * SLOT_CAP + m0) * 64;
#pragma unroll
            for (int i = 0; i < 4; ++i)
                gl_lds16(ab + i * 2048 + lin, Al + i * 2048 + wv * 512);
        }
        // ---- stage B ----
        if (WH) {
            const unsigned short* bb = Bh + ((size_t)(e * KT + kt) * ND + n0) * 64;
#pragma unroll
            for (int i = 0; i < 4; ++i)
                gl_lds16(bb + i * 2048 + lin, Bl + i * 2048 + wv * 512);
        } else {
            const float* Wf = Bf + (size_t)e * KD * ND;
            const int kb = (wv >> 1) * 32 + (lane >> 4) * 8;
            const int n4 = (wv & 1) * 64 + (lane & 15) * 4;
            f32x4 r[8];
#pragma unroll
            for (int rr = 0; rr < 8; ++rr)
                r[rr] = *reinterpret_cast<const f32x4*>(
                    Wf + (size_t)(kt * 64 + kb + rr) * ND + n0 + n4);
#pragma unroll
            for (int m = 0; m < 4; ++m) {
                f16x8 v;
#pragma unroll
                for (int rr = 0; rr < 8; ++rr) v[rr] = (_Float16)r[rr][m];
                int nn = n4 + m;
                *reinterpret_cast<f16x8*>(Blc + nn * 128 + (((kb >> 3) ^ (nn & 7)) << 4)) = v;
            }
        }
        __syncthreads();
        // ---- compute ----
#pragma unroll
        for (int kc = 0; kc < 2; ++kc) {
            const int cb = kc * 4 + (lane >> 4);  // k-chunk index (8 fp16 each)
            f16x8 af[4], bf[4];
#pragma unroll
            for (int mi = 0; mi < 4; ++mi) {
                int row = wm * 64 + mi * 16 + (lane & 15);
                af[mi] = *reinterpret_cast<const f16x8*>(Alc + row * 128 + ((cb ^ (row & 7)) << 4));
            }
#pragma unroll
            for (int ni = 0; ni < 4; ++ni) {
                int col = wn * 64 + ni * 16 + (lane & 15);
                bf[ni] = *reinterpret_cast<const f16x8*>(Blc + col * 128 + ((cb ^ (col & 7)) << 4));
            }
#pragma unroll
            for (int mi = 0; mi < 4; ++mi)
#pragma unroll
                for (int ni = 0; ni < 4; ++ni)
                    acc[mi][ni] = __builtin_amdgcn_mfma_f32_16x16x32_f16(
                        af[mi], bf[ni], acc[mi][ni], 0, 0, 0);
        }
        __syncthreads();
    }

    // ---- epilogue ----
#pragma unroll
    for (int mi = 0; mi < 4; ++mi) {
#pragma unroll
        for (int rr = 0; rr < 4; ++rr) {
            const int srow = m0 + wm * 64 + mi * 16 + (lane >> 4) * 4 + rr;
            if (PHASE == 1) {
#pragma unroll
                for (int ni = 0; ni < 4; ++ni) {
                    int col = n0 + wn * 64 + ni * 16 + (lane & 15);
                    float v = acc[mi][ni][rr];
                    float g = 0.5f * v * (1.f + erff(v * 0.70710678118654752f));
                    int kt2 = col >> 6, kl = col & 63;
                    Hout[((size_t)kt2 * SLOT_CAP + srow) * 64 +
                         (((kl >> 3) ^ (srow & 7)) << 3) + (kl & 7)] = f2h(g);
                }
            } else {
                int tok = tos[srow];
                float gate = gos[srow];
                float* orow = Out + (size_t)tok * DIM + n0 + wn * 64 + (lane & 15);
#pragma unroll
                for (int ni = 0; ni < 4; ++ni)
                    atomicAdd(&orow[ni * 16], gate * acc[mi][ni][rr]);
            }
        }
    }
}

// ---------------- launch ----------------
extern "C" void kernel_launch(void* const* d_in, const int* in_sizes, int n_in,
                              void* d_out, int out_size, void* d_ws, size_t ws_size,
                              hipStream_t stream) {
    (void)in_sizes; (void)n_in;
    const float* x  = (const float*)d_in[0];
    const float* Wr = (const float*)d_in[1];
    const float* W1 = (const float*)d_in[2];
    const float* W2 = (const float*)d_in[3];
    float* out = (float*)d_out;
    char* ws = (char*)d_ws;

    // ws layout (bytes):
    //   0          ctl
    //   4096       tok2e (2N i32)
    //   69632      tok2w (2N f32)
    //   135168     tos (SLOT_CAP i32)
    //   204800     gos (SLOT_CAP f32)
    //   274432     xh fp16 (N*DIM)                    -> ends 17,051,648
    //   17051648   H2 fp16 tile-format (64*SLOT_CAP*64) -> ends 159,657,984
    //   159657984  Wt fp16 (67,108,864, reused W1t then W2t) -> ends 226,766,848
    const size_t NEED_FB   = 159657984ULL;
    const size_t NEED_FULL = 226766848ULL;
    if (ws_size < NEED_FB) return;
    const bool big = ws_size >= NEED_FULL;

    int*            ctl = (int*)(ws + 0);
    int*            t2e = (int*)(ws + 4096);
    float*          t2w = (float*)(ws + 69632);
    int*            tos = (int*)(ws + 135168);
    float*          gos = (float*)(ws + 204800);
    unsigned short* xh  = (unsigned short*)(ws + 274432);
    unsigned short* H2  = (unsigned short*)(ws + 17051648);
    unsigned short* Wt  = (unsigned short*)(ws + 159657984);

    hipMemsetAsync(ctl, 0, 64, stream);
    hipMemsetAsync(d_out, 0, (size_t)out_size * 4, stream);

    k_router <<<dim3(N_TOK / 4), dim3(256), 0, stream>>>(x, Wr, xh, ctl, t2e, t2w);
    k_setup  <<<dim3(1), dim3(64), 0, stream>>>(ctl, tos, gos);
    k_scatter<<<dim3(N_TOK / 256), dim3(256), 0, stream>>>(t2e, t2w, ctl, tos, gos);

    if (big) {
        k_wcvt<<<dim3(64, 16, 8), dim3(256), 0, stream>>>(W1, Wt, DIM, FF);
        k_gemm<1, true><<<dim3(FF / BN, MAXT), dim3(256), 0, stream>>>(
            xh, Wt, nullptr, H2, nullptr, ctl, tos, gos);
        k_wcvt<<<dim3(16, 64, 8), dim3(256), 0, stream>>>(W2, Wt, FF, DIM);
        k_gemm<2, true><<<dim3(DIM / BN, MAXT), dim3(256), 0, stream>>>(
            H2, Wt, nullptr, nullptr, out, ctl, tos, gos);
    } else {
        k_gemm<1, false><<<dim3(FF / BN, MAXT), dim3(256), 0, stream>>>(
            xh, nullptr, W1, H2, nullptr, ctl, tos, gos);
        k_gemm<2, false><<<dim3(DIM / BN, MAXT), dim3(256), 0, stream>>>(
            H2, nullptr, W2, nullptr, out, ctl, tos, gos);
    }
}